// Round 7
// baseline (354.653 us; speedup 1.0000x reference)
//
#include <hip/hip_runtime.h>
#include <cstdint>
#include <cstddef>

using bf16x8 = __attribute__((ext_vector_type(8))) short;
using f32x4  = __attribute__((ext_vector_type(4))) float;

#define DI __device__ __forceinline__

DI float bnv(float x, float g, float b, float m, float v) {
    return (x - m) * (g / sqrtf(v + 1e-5f)) + b;
}
DI unsigned short sgn_bf16(float v) {
    return (v >= 0.f) ? (unsigned short)0x3F80 : (unsigned short)0xBF80;
}
// psum ADC quantization on pre-scaled acc (= p/16): clip(rne(acc), -8, 7); x16 folded into bn
DI float pq_scaled(float a) {
    float q = rintf(a);
    return fminf(7.f, fmaxf(-8.f, q));
}

// ---------------- conv0 (full precision) + bn0 + sign -> b-packed bf16 ------
// out layout: [y32][x32][cblk20][b64][8c]  (grouping for L1: Cin=128, chunk 14)
__global__ __launch_bounds__(256)
void k_conv0(const float* __restrict__ x, const float* __restrict__ w,
             const float* __restrict__ bnp, unsigned short* __restrict__ out) {
    __shared__ float sX[3][3][36];
    const int b = blockIdx.x >> 5, y = blockIdx.x & 31;
    const int tid = threadIdx.x;
    const int o = tid & 127, xc = tid >> 7;

    for (int i = tid; i < 3 * 3 * 36; i += 256) {
        int col = i % 36, rr = (i / 36) % 3, c = i / 108;
        int gy = y + rr - 1, gx = col - 1;
        float v = 0.f;
        if ((unsigned)gy < 32u && (unsigned)gx < 32u)
            v = x[((b * 3 + c) * 32 + gy) * 32 + gx];
        sX[c][rr][col] = v;
    }
    float wr[27];
    const float* wp = w + o * 27;
    #pragma unroll
    for (int t = 0; t < 27; ++t) wr[t] = wp[t];
    __syncthreads();

    const float bg = bnp[o], bb = bnp[128 + o], bm = bnp[256 + o], bv = bnp[384 + o];
    const int cb0 = (o / 14) * 2 + ((o % 14) >> 3);
    const int sl0 = (o % 14) & 7;
    unsigned short* op = out + (size_t)(y * 32) * 10240 + (size_t)cb0 * 512
                             + (size_t)b * 8 + sl0;

    #pragma unroll
    for (int q = 0; q < 4; ++q) {
        float acc0 = 0.f, acc1 = 0.f, acc2 = 0.f, acc3 = 0.f;
        const int X0 = xc * 16 + q * 4;
        #pragma unroll
        for (int c = 0; c < 3; ++c)
            #pragma unroll
            for (int ky = 0; ky < 3; ++ky) {
                float xv0 = sX[c][ky][X0 + 0], xv1 = sX[c][ky][X0 + 1];
                float xv2 = sX[c][ky][X0 + 2], xv3 = sX[c][ky][X0 + 3];
                float xv4 = sX[c][ky][X0 + 4], xv5 = sX[c][ky][X0 + 5];
                float w0 = wr[c * 9 + ky * 3 + 0];
                float w1 = wr[c * 9 + ky * 3 + 1];
                float w2 = wr[c * 9 + ky * 3 + 2];
                acc0 += xv0 * w0 + xv1 * w1 + xv2 * w2;
                acc1 += xv1 * w0 + xv2 * w1 + xv3 * w2;
                acc2 += xv2 * w0 + xv3 * w1 + xv4 * w2;
                acc3 += xv3 * w0 + xv4 * w1 + xv5 * w2;
            }
        op[(size_t)(X0 + 0) * 10240] = sgn_bf16(bnv(acc0, bg, bb, bm, bv));
        op[(size_t)(X0 + 1) * 10240] = sgn_bf16(bnv(acc1, bg, bb, bm, bv));
        op[(size_t)(X0 + 2) * 10240] = sgn_bf16(bnv(acc2, bg, bb, bm, bv));
        op[(size_t)(X0 + 3) * 10240] = sgn_bf16(bnv(acc3, bg, bb, bm, bv));
    }
}

// ---------------- weight pack: wpk[g][tap10][chdw2][o][8c], values +-1/16 ----
__global__ __launch_bounds__(256)
void k_pack_w(const float* __restrict__ w, unsigned short* __restrict__ wpk,
              int Cin, int O, int G) {
    int idx = blockIdx.x * 256 + threadIdx.x;
    if (idx >= G * O * 160) return;
    int c8 = idx & 7;
    int o  = (idx >> 3) % O;
    int r2 = (idx >> 3) / O;
    int chdw = r2 & 1, tap = (r2 >> 1) % 10, g = r2 / 20;
    int c = chdw * 8 + c8, cg = g * 14 + c;
    unsigned short v = 0;
    if (tap < 9 && c < 14 && cg < Cin)
        v = (w[((size_t)o * Cin + cg) * 9 + tap] >= 0.f) ? (unsigned short)0x3D80
                                                         : (unsigned short)0xBD80;
    wpk[idx] = v;
}

// ---------------- batch-M MFMA crossbar conv (no LDS, no barriers) ----------
// act: [y][x][cblk(=2G)][b64][8] bf16.  wave = 16 batches (bg), 64 o, MS pixels.
// OUTMODE 0: bn+sign -> act-out;  1: in-lane quad pool + bn + sign -> act-out;
//         2: raw tot -> P f32 [px][o][b]  (L5; pool in separate epilogue)
template <int H, int W, int CB, int O, int G, int MS, int OUTMODE, int OUTCB, int MINW>
__global__ __launch_bounds__(256, MINW)
void k_conv_bm(const char* __restrict__ act, const char* __restrict__ wpk,
               const float* __restrict__ bnp, unsigned short* __restrict__ outa,
               float* __restrict__ P) {
    static_assert(OUTMODE != 1 || MS == 4, "pool mode needs quad");
    const int tid = threadIdx.x;
    const int lane = tid & 63, bg = tid >> 6;
    const int n = lane & 15, kb = lane >> 4, hb = kb >> 1, chdw = kb & 1;
    const int sp = blockIdx.x;
    const int o0 = blockIdx.y * 64;

    int pix[MS];
    int qY = 0, qX = 0;
    if constexpr (MS == 4) {
        qY = sp / (W / 2); qX = sp % (W / 2);
        #pragma unroll
        for (int ms = 0; ms < 4; ++ms)
            pix[ms] = (2 * qY + (ms >> 1)) * W + 2 * qX + (ms & 1);
    } else {
        pix[0] = sp;
    }

    const int bl = (bg * 16 + n) * 16 + chdw * 1024;
    int off[MS][5];
    #pragma unroll
    for (int ms = 0; ms < MS; ++ms) {
        int py = pix[ms] / W, px = pix[ms] % W;
        #pragma unroll
        for (int s = 0; s < 5; ++s) {
            int t = 2 * s + hb;
            int ty = t / 3, tx = t - 3 * ty;
            int gy = py + ty - 1, gx = px + tx - 1;
            bool valid = (t <= 8) && ((unsigned)gy < (unsigned)H) && ((unsigned)gx < (unsigned)W);
            off[ms][s] = valid ? ((gy * W + gx) * CB) * 1024 + bl : (int)0xC0000000;
        }
    }

    const char* wl = wpk + (size_t)(((hb * 2 + chdw) * O) + o0 + n) * 16;

    float tot[MS][4][4];
    #pragma unroll
    for (int ms = 0; ms < MS; ++ms)
        #pragma unroll
        for (int nt = 0; nt < 4; ++nt)
            #pragma unroll
            for (int r = 0; r < 4; ++r) tot[ms][nt][r] = 0.f;

    const bf16x8 az = {0, 0, 0, 0, 0, 0, 0, 0};

    #pragma unroll 1
    for (int g = 0; g < G; ++g) {
        f32x4 acc[MS][4];
        #pragma unroll
        for (int ms = 0; ms < MS; ++ms)
            #pragma unroll
            for (int nt = 0; nt < 4; ++nt) acc[ms][nt] = (f32x4){0.f, 0.f, 0.f, 0.f};

        const char* wg = wl + (size_t)g * (20 * O * 16);
        const char* ag = act + (size_t)g * 2048;
        #pragma unroll
        for (int s = 0; s < 5; ++s) {
            bf16x8 bq[4];
            #pragma unroll
            for (int nt = 0; nt < 4; ++nt)
                bq[nt] = *(const bf16x8*)(wg + s * (4 * O * 16) + nt * 256);
            #pragma unroll
            for (int ms = 0; ms < MS; ++ms) {
                bf16x8 af = az;
                int ofs = off[ms][s];
                if (ofs >= 0) af = *(const bf16x8*)(ag + ofs);
                #pragma unroll
                for (int nt = 0; nt < 4; ++nt)
                    acc[ms][nt] = __builtin_amdgcn_mfma_f32_16x16x32_bf16(af, bq[nt], acc[ms][nt], 0, 0, 0);
            }
        }
        #pragma unroll
        for (int ms = 0; ms < MS; ++ms)
            #pragma unroll
            for (int nt = 0; nt < 4; ++nt)
                #pragma unroll
                for (int r = 0; r < 4; ++r)
                    tot[ms][nt][r] += pq_scaled(acc[ms][nt][r]);
    }

    const int bb = bg * 16 + kb * 4;
    if constexpr (OUTMODE == 2) {
        #pragma unroll
        for (int nt = 0; nt < 4; ++nt) {
            int oc = o0 + nt * 16 + n;
            #pragma unroll
            for (int r = 0; r < 4; ++r)
                P[((size_t)pix[0] * 512 + oc) * 64 + bb + r] = tot[0][nt][r];
        }
    } else {
        #pragma unroll
        for (int nt = 0; nt < 4; ++nt) {
            int oc = o0 + nt * 16 + n;
            float g_ = bnp[oc], b_ = bnp[O + oc], m_ = bnp[2 * O + oc], v_ = bnp[3 * O + oc];
            int q14 = oc / 14, r14 = oc - 14 * q14;
            int cb = 2 * q14 + (r14 >> 3), sl = r14 & 7;
            int ppos = (OUTMODE == 1) ? (qY * (W / 2) + qX) : pix[0];
            #pragma unroll
            for (int r = 0; r < 4; ++r) {
                float v;
                if constexpr (OUTMODE == 1)
                    v = fmaxf(fmaxf(tot[0][nt][r], tot[1][nt][r]),
                              fmaxf(tot[2][nt][r], tot[3][nt][r]));
                else
                    v = tot[0][nt][r];
                float val = bnv(16.f * v, g_, b_, m_, v_);
                outa[((size_t)ppos * OUTCB + cb) * 512 + (size_t)(bb + r) * 8 + sl] = sgn_bf16(val);
            }
        }
    }
}

// ---------------- L5 epilogue: pool + bn + sign + pack to a5p ---------------
__global__ __launch_bounds__(256)
void k_ep_pool5(const float* __restrict__ P, const float* __restrict__ bnp,
                unsigned short* __restrict__ a5p) {
    int idx = blockIdx.x * 256 + threadIdx.x;   // 64b x 512o x 16pq
    int b = idx & 63;
    int o = (idx >> 6) & 511;
    int pq = idx >> 15;
    int py = pq >> 2, px = pq & 3;
    const float* p0 = P + ((size_t)(2 * py * 8 + 2 * px) * 512 + o) * 64 + b;
    const int dx = 512 * 64, dy = 8 * 512 * 64;
    float v = fmaxf(fmaxf(p0[0], p0[dx]), fmaxf(p0[dy], p0[dy + dx]));
    float val = bnv(16.f * v, bnp[o], bnp[512 + o], bnp[1024 + o], bnp[1536 + o]);
    int d = o * 16 + py * 4 + px;
    a5p[((size_t)(d >> 3) * 64 + b) * 8 + (d & 7)] = sgn_bf16(val);
}

// ---------------- MFMA psum fc (unchanged) ----------------------------------
DI float pq16(float ps) {
    float q = rintf(ps * 0.0625f);
    q = fminf(7.f, fmaxf(-8.f, q));
    return q * 16.f;
}

template <int D, int GPB>
__global__ __launch_bounds__(256)
void k_fc_mfma(const unsigned short* __restrict__ bpk, const float* __restrict__ w,
               float* __restrict__ accg) {
    const int lane = threadIdx.x & 63, wv = threadIdx.x >> 6;
    const int n = lane & 15, kb = lane >> 4;
    const int orow = blockIdx.x * 64 + wv * 16 + n;
    const int g0 = blockIdx.y * GPB;

    float tot[4][4];
    #pragma unroll
    for (int s = 0; s < 4; ++s)
        #pragma unroll
        for (int r = 0; r < 4; ++r) tot[s][r] = 0.f;

    #pragma unroll 1
    for (int g = 0; g < GPB; ++g) {
        const int kbase = (g0 + g) * 128;
        f32x4 a0 = {0,0,0,0}, a1 = {0,0,0,0}, a2 = {0,0,0,0}, a3 = {0,0,0,0};
        #pragma unroll
        for (int s = 0; s < 4; ++s) {
            const int k0 = kbase + s * 32 + kb * 8;
            const float* wp = w + (size_t)orow * D + k0;
            float4 wlo = *(const float4*)wp;
            float4 whi = *(const float4*)(wp + 4);
            bf16x8 af;
            af[0] = (short)sgn_bf16(wlo.x); af[1] = (short)sgn_bf16(wlo.y);
            af[2] = (short)sgn_bf16(wlo.z); af[3] = (short)sgn_bf16(wlo.w);
            af[4] = (short)sgn_bf16(whi.x); af[5] = (short)sgn_bf16(whi.y);
            af[6] = (short)sgn_bf16(whi.z); af[7] = (short)sgn_bf16(whi.w);
            const unsigned short* bp = bpk + (size_t)(k0 >> 3) * 512;
            bf16x8 b0 = *(const bf16x8*)(bp + (n +  0) * 8);
            bf16x8 b1 = *(const bf16x8*)(bp + (n + 16) * 8);
            bf16x8 b2 = *(const bf16x8*)(bp + (n + 32) * 8);
            bf16x8 b3 = *(const bf16x8*)(bp + (n + 48) * 8);
            a0 = __builtin_amdgcn_mfma_f32_16x16x32_bf16(af, b0, a0, 0, 0, 0);
            a1 = __builtin_amdgcn_mfma_f32_16x16x32_bf16(af, b1, a1, 0, 0, 0);
            a2 = __builtin_amdgcn_mfma_f32_16x16x32_bf16(af, b2, a2, 0, 0, 0);
            a3 = __builtin_amdgcn_mfma_f32_16x16x32_bf16(af, b3, a3, 0, 0, 0);
        }
        #pragma unroll
        for (int r = 0; r < 4; ++r) {
            tot[0][r] += pq16(a0[r]); tot[1][r] += pq16(a1[r]);
            tot[2][r] += pq16(a2[r]); tot[3][r] += pq16(a3[r]);
        }
    }
    const int od = blockIdx.x * 64 + wv * 16 + kb * 4;
    #pragma unroll
    for (int s = 0; s < 4; ++s)
        #pragma unroll
        for (int r = 0; r < 4; ++r)
            atomicAdd(&accg[(size_t)(od + r) * 64 + s * 16 + n], tot[s][r]);
}

template <bool SIGN>
__global__ __launch_bounds__(256)
void k_fc_ep(const float* __restrict__ accg, const float* __restrict__ bnp,
             unsigned short* __restrict__ packed, float* __restrict__ h2, int O) {
    int idx = blockIdx.x * 256 + threadIdx.x;
    int b = idx & 63, o = idx >> 6;
    float val = bnv(accg[idx], bnp[o], bnp[O + o], bnp[2 * O + o], bnp[3 * O + o]);
    if (SIGN) packed[((size_t)(o >> 3) * 64 + b) * 8 + (o & 7)] = sgn_bf16(val);
    else      h2[(size_t)b * 1024 + o] = val;
}

__global__ __launch_bounds__(64)
void k_out(const float* __restrict__ h2, const float* __restrict__ ow,
           const float* __restrict__ ob, const float* __restrict__ bnp,
           float* __restrict__ out) {
    int b = blockIdx.x / 10, o = blockIdx.x % 10;
    int lane = threadIdx.x;
    float acc = 0.f;
    #pragma unroll
    for (int i = 0; i < 16; ++i) {
        int k = i * 64 + lane;
        acc += h2[b * 1024 + k] * ow[o * 1024 + k];
    }
    #pragma unroll
    for (int off = 32; off; off >>= 1) acc += __shfl_xor(acc, off);
    if (lane == 0)
        out[b * 10 + o] = bnv(acc + ob[o], bnp[o], bnp[10 + o], bnp[20 + o], bnp[30 + o]);
}

extern "C" void kernel_launch(void* const* d_in, const int* in_sizes, int n_in,
                              void* d_out, int out_size, void* d_ws, size_t ws_size,
                              hipStream_t stream) {
    const float* x     = (const float*)d_in[0];
    const float* w0    = (const float*)d_in[1];
    const float* bn0   = (const float*)d_in[2];
    const float* w1    = (const float*)d_in[3];
    const float* bn1   = (const float*)d_in[4];
    const float* w2    = (const float*)d_in[5];
    const float* bn2   = (const float*)d_in[6];
    const float* w3    = (const float*)d_in[7];
    const float* bn3   = (const float*)d_in[8];
    const float* w4    = (const float*)d_in[9];
    const float* bn4   = (const float*)d_in[10];
    const float* w5    = (const float*)d_in[11];
    const float* bn5   = (const float*)d_in[12];
    const float* fc1w  = (const float*)d_in[13];
    const float* bnf1  = (const float*)d_in[14];
    const float* fc2w  = (const float*)d_in[15];
    const float* bnf2  = (const float*)d_in[16];
    const float* outw  = (const float*)d_in[17];
    const float* outb  = (const float*)d_in[18];
    const float* bnout = (const float*)d_in[19];

    char* ws = (char*)d_ws;
    char*           ping  = ws;                                 // 20,971,520 B
    char*           pong  = ws + 20971520;                      //  5,242,880 B
    unsigned short* wpk   = (unsigned short*)(ws + 26214400);   //  6,291,456 B
    float*          P     = (float*)(ws + 32505856);            //  8,388,608 B [64px][512o][64b]
    unsigned short* a5p   = (unsigned short*)(ws + 40894464);   //  1,048,576 B
    unsigned short* a6p   = (unsigned short*)(ws + 41943040);   //    131,072 B
    float*          h1acc = (float*)(ws + 42074112);            //    262,144 B
    float*          h2acc = (float*)(ws + 42336256);            //    262,144 B
    float*          h2    = (float*)(ws + 42598400);            //    262,144 B
    const char*     wpkc  = (const char*)wpk;

    hipMemsetAsync(h1acc, 0, 262144, stream);
    hipMemsetAsync(h2acc, 0, 262144, stream);

    // conv0 -> ping [32][32][20][64][8]
    k_conv0<<<dim3(2048), dim3(256), 0, stream>>>(x, w0, bn0, (unsigned short*)ping);

    // L1: 128->128 @32, quad pool fused -> pong [16][16][20][64][8]
    k_pack_w<<<dim3(800), dim3(256), 0, stream>>>(w1, wpk, 128, 128, 10);
    k_conv_bm<32, 32, 20, 128, 10, 4, 1, 20, 2>
        <<<dim3(256, 2), dim3(256), 0, stream>>>(ping, wpkc, bn1, (unsigned short*)pong, nullptr);

    // L2: 128->256 @16 -> ping [16][16][38][64][8]
    k_pack_w<<<dim3(1600), dim3(256), 0, stream>>>(w2, wpk, 128, 256, 10);
    k_conv_bm<16, 16, 20, 256, 10, 1, 0, 38, 4>
        <<<dim3(256, 4), dim3(256), 0, stream>>>(pong, wpkc, bn2, (unsigned short*)ping, nullptr);

    // L3: 256->256 @16, quad pool fused -> pong [8][8][38][64][8]
    k_pack_w<<<dim3(3040), dim3(256), 0, stream>>>(w3, wpk, 256, 256, 19);
    k_conv_bm<16, 16, 38, 256, 19, 4, 1, 38, 2>
        <<<dim3(64, 4), dim3(256), 0, stream>>>(ping, wpkc, bn3, (unsigned short*)pong, nullptr);

    // L4: 256->512 @8 -> ping [8][8][74][64][8]
    k_pack_w<<<dim3(6080), dim3(256), 0, stream>>>(w4, wpk, 256, 512, 19);
    k_conv_bm<8, 8, 38, 512, 19, 1, 0, 74, 4>
        <<<dim3(64, 8), dim3(256), 0, stream>>>(pong, wpkc, bn4, (unsigned short*)ping, nullptr);

    // L5: 512->512 @8 -> P raw tot, then pool+bn+sign+pack -> a5p
    k_pack_w<<<dim3(11840), dim3(256), 0, stream>>>(w5, wpk, 512, 512, 37);
    k_conv_bm<8, 8, 74, 512, 37, 1, 2, 1, 4>
        <<<dim3(64, 8), dim3(256), 0, stream>>>(ping, wpkc, nullptr, nullptr, P);
    k_ep_pool5<<<dim3(2048), dim3(256), 0, stream>>>(P, bn5, a5p);

    // fc1 / fc2 / out
    k_fc_mfma<8192, 1><<<dim3(16, 64), dim3(256), 0, stream>>>(a5p, fc1w, h1acc);
    k_fc_ep<true><<<dim3(256), dim3(256), 0, stream>>>(h1acc, bnf1, a6p, nullptr, 1024);
    k_fc_mfma<1024, 1><<<dim3(16, 8), dim3(256), 0, stream>>>(a6p, fc2w, h2acc);
    k_fc_ep<false><<<dim3(256), dim3(256), 0, stream>>>(h2acc, bnf2, nullptr, h2, 1024);
    k_out<<<dim3(640), dim3(64), 0, stream>>>(h2, outw, outb, bnout, (float*)d_out);
}